// Round 12
// baseline (48.288 us; speedup 1.0000x reference)
//
#include <hip/hip_runtime.h>

// Depthwise 7x7 'same' conv, fp32 in/out. B=16, C=256, H=W=64.
// FLAT decomposition: one thread = one output row x 4 cols. No vertical
// strip, no rotating buffer, no LDS. Block = 16 rows x 64 cols of one
// plane (input slice ~5.6 KB -> L1-resident vertical reuse).
// Rationale (R10/R11 ledger): unrolled ~20KB bodies cap at 36-41%
// VALUBusy (issue/fetch-starved); small bodies issue at 64%+ (R11) but
// rotating-buffer spilled (VGPR=28). This kernel: body ~2.5 KB, static
// weight indices, live state ~50 VGPR -> 8 waves/SIMD, 65k waves TLP.
// Math: R10-verified dot2 path (fp16 inputs, f32 accum, 3 dot2 + 1 fma
// per 7-tap row; absmax 0.25 vs threshold 0.855).

typedef _Float16 v2h __attribute__((ext_vector_type(2)));

static __device__ __forceinline__ v2h pack2(float a, float b) {
    return __builtin_bit_cast(v2h, __builtin_amdgcn_cvt_pkrtz(a, b));
}

__global__ __launch_bounds__(256)
void dwconv7x7_flat(const float* __restrict__ x,
                    const float* __restrict__ weight,
                    const float* __restrict__ bias,
                    float* __restrict__ out) {
    const int tid   = threadIdx.x;
    const int bk    = blockIdx.x;
    const int plane = bk >> 2;          // b*256 + c  (block-uniform)
    const int c     = plane & 255;      // scalar

    // ---- per-channel weights (block-uniform): half2 pairs in SGPRs ----
    const float* wp = weight + c * 49;
    float wk[49];
#pragma unroll
    for (int k = 0; k < 49; ++k) wk[k] = wp[k];
    const float bv = bias[c];

    v2h  W[7][3];     // taps (0,1),(2,3),(4,5) per kernel row
    float w6[7];      // tap 6 scalar
#pragma unroll
    for (int kr = 0; kr < 7; ++kr) {
#pragma unroll
        for (int t = 0; t < 3; ++t) {
            v2h p = pack2(wk[kr * 7 + 2 * t], wk[kr * 7 + 2 * t + 1]);
            int b = __builtin_amdgcn_readfirstlane(__builtin_bit_cast(int, p));
            W[kr][t] = __builtin_bit_cast(v2h, b);
        }
        w6[kr] = wk[kr * 7 + 6];
    }

    const int tx   = tid & 15;                  // 16 col-groups
    const int ty   = tid >> 4;                  // 16 rows per block
    const int orow = (bk & 3) * 16 + ty;        // output row 0..63
    const int wb   = tx * 4;                    // output col base

    const float* xp = x + (size_t)plane * 4096;
    const int offm = (tx > 0)  ? (wb - 4) : wb; // clamped aligned left
    const int offp = (tx < 15) ? (wb + 4) : wb; // clamped aligned right

    float a0 = 0.f, a1 = 0.f, a2 = 0.f, a3 = 0.f;

#pragma unroll
    for (int kr = 0; kr < 7; ++kr) {
        const int r  = orow - 3 + kr;
        const int rc = min(max(r, 0), 63);
        const float* rowp = xp + rc * 64;
        const bool mrow = (r >= 0) && (r < 64);
        const bool mm = mrow && (tx > 0);
        const bool mp = mrow && (tx < 15);

        float4 qm = *reinterpret_cast<const float4*>(rowp + offm);
        float4 q0 = *reinterpret_cast<const float4*>(rowp + wb);
        float4 qp = *reinterpret_cast<const float4*>(rowp + offp);

        // f[i] = x[r][wb-3+i], i = 0..9 (masked to zero outside)
        float f[10];
        f[0] = mm   ? qm.y : 0.f;
        f[1] = mm   ? qm.z : 0.f;
        f[2] = mm   ? qm.w : 0.f;
        f[3] = mrow ? q0.x : 0.f;
        f[4] = mrow ? q0.y : 0.f;
        f[5] = mrow ? q0.z : 0.f;
        f[6] = mrow ? q0.w : 0.f;
        f[7] = mp   ? qp.x : 0.f;
        f[8] = mp   ? qp.y : 0.f;
        f[9] = mp   ? qp.z : 0.f;

        // sliding half2 pairs: pk[t] = (f[t], f[t+1])
        v2h pk[8];
#pragma unroll
        for (int t = 0; t < 8; ++t) pk[t] = pack2(f[t], f[t + 1]);

        // output col wb+jj: taps kc -> f[jj+kc]; kr is COMPILE-TIME here
        a0 = fmaf(f[6], w6[kr], a0);
        a0 = __builtin_amdgcn_fdot2(pk[4], W[kr][2], a0, false);
        a0 = __builtin_amdgcn_fdot2(pk[2], W[kr][1], a0, false);
        a0 = __builtin_amdgcn_fdot2(pk[0], W[kr][0], a0, false);

        a1 = fmaf(f[7], w6[kr], a1);
        a1 = __builtin_amdgcn_fdot2(pk[5], W[kr][2], a1, false);
        a1 = __builtin_amdgcn_fdot2(pk[3], W[kr][1], a1, false);
        a1 = __builtin_amdgcn_fdot2(pk[1], W[kr][0], a1, false);

        a2 = fmaf(f[8], w6[kr], a2);
        a2 = __builtin_amdgcn_fdot2(pk[6], W[kr][2], a2, false);
        a2 = __builtin_amdgcn_fdot2(pk[4], W[kr][1], a2, false);
        a2 = __builtin_amdgcn_fdot2(pk[2], W[kr][0], a2, false);

        a3 = fmaf(f[9], w6[kr], a3);
        a3 = __builtin_amdgcn_fdot2(pk[7], W[kr][2], a3, false);
        a3 = __builtin_amdgcn_fdot2(pk[5], W[kr][1], a3, false);
        a3 = __builtin_amdgcn_fdot2(pk[3], W[kr][0], a3, false);
    }

    // ---- store 1 float4 per thread (wave: 4 rows x 64 cols, coalesced) ----
    float4 v;
    v.x = a0 + bv;
    v.y = a1 + bv;
    v.z = a2 + bv;
    v.w = a3 + bv;
    *reinterpret_cast<float4*>(out + (size_t)plane * 4096 + orow * 64 + wb) = v;
}

extern "C" void kernel_launch(void* const* d_in, const int* in_sizes, int n_in,
                              void* d_out, int out_size, void* d_ws, size_t ws_size,
                              hipStream_t stream) {
    const float* x      = (const float*)d_in[0];
    const float* weight = (const float*)d_in[1];
    const float* bias   = (const float*)d_in[2];
    float* out          = (float*)d_out;
    (void)in_sizes; (void)n_in; (void)out_size; (void)d_ws; (void)ws_size;

    // 4096 planes x 4 blocks (16 rows each) = 16384 blocks x 256 threads
    dim3 grid(16384);
    dim3 block(256);
    dwconv7x7_flat<<<grid, block, 0, stream>>>(x, weight, bias, out);
}

// Round 13
// 35.179 us; speedup vs baseline: 1.3726x; 1.3726x over previous
//
#include <hip/hip_runtime.h>

// Depthwise 7x7 'same' conv, fp32 in/out. B=16, C=256, H=W=64.
// Quarter-plane waves: same verified dot2 math + masked-load mapping as
// R10 (best, 34.2us), unit shrunk 2x. wave = quarter-plane (16 rows),
// lane = 4 cols x 4 rows = 16 acc, 10 row-steps, body ~6 KB.
// Ledger rationale: wall ~ VALU-work / VALUBusy. R10: 45 instr/out @36%
// busy; R12 (flat): 79 @57%. This point: ~54 @ (predicted) 55-65% via
// small unit + 2x grid (16384 waves) + ~64 VGPR -> 8 waves/SIMD.

typedef _Float16 v2h __attribute__((ext_vector_type(2)));

static __device__ __forceinline__ v2h pack2(float a, float b) {
    return __builtin_bit_cast(v2h, __builtin_amdgcn_cvt_pkrtz(a, b));
}

__global__ void dwconv7x7_quarter(const float* __restrict__ x,
                                  const float* __restrict__ weight,
                                  const float* __restrict__ bias,
                                  float* __restrict__ out) {
    const int tid  = threadIdx.x;
    const int lane = tid & 63;
    const int wid  = tid >> 6;
    const int gw   = blockIdx.x * 4 + wid;   // 0..16383
    const int plane = gw >> 2;               // b*256 + c
    const int quart = gw & 3;                // 16-row band
    const int c = __builtin_amdgcn_readfirstlane(plane & 255);

    // ---- per-channel weights (uniform): half2 pairs in SGPRs ----
    const float* wp = weight + c * 49;
    float wk[49];
#pragma unroll
    for (int k = 0; k < 49; ++k) wk[k] = wp[k];
    const float bv = bias[c];

    v2h  W[7][3];     // taps (0,1),(2,3),(4,5) per kernel row
    float w6[7];      // tap 6 scalar
#pragma unroll
    for (int kr = 0; kr < 7; ++kr) {
#pragma unroll
        for (int t = 0; t < 3; ++t) {
            v2h p = pack2(wk[kr * 7 + 2 * t], wk[kr * 7 + 2 * t + 1]);
            int b = __builtin_amdgcn_readfirstlane(__builtin_bit_cast(int, p));
            W[kr][t] = __builtin_bit_cast(v2h, b);
        }
        w6[kr] = wk[kr * 7 + 6];
    }

    const int tx = lane & 15;        // 16 tiles across width
    const int sy = lane >> 4;        // 4 strips per quarter
    const int wb = tx * 4;           // output col base
    const int hb = quart * 16 + sy * 4;   // output row base

    const float* xp = x + (size_t)plane * 4096;
    const int offm = (tx > 0)  ? (wb - 4) : wb;   // clamped aligned left
    const int offp = (tx < 15) ? (wb + 4) : wb;   // clamped aligned right

    float acc[4][4];
#pragma unroll
    for (int i = 0; i < 4; ++i)
#pragma unroll
        for (int j = 0; j < 4; ++j) acc[i][j] = 0.f;

    // Stream input rows hb-3 .. hb+6 (10 steps).
#pragma unroll
    for (int j = 0; j < 10; ++j) {
        const int r  = hb - 3 + j;
        const int rc = min(max(r, 0), 63);
        const float* rowp = xp + rc * 64;
        const bool mrow = (r >= 0) && (r < 64);
        const bool mm = mrow && (tx > 0);
        const bool mp = mrow && (tx < 15);

        float4 qm = *reinterpret_cast<const float4*>(rowp + offm);
        float4 q0 = *reinterpret_cast<const float4*>(rowp + wb);
        float4 qp = *reinterpret_cast<const float4*>(rowp + offp);

        // f[i] = x[r][wb-3+i], i = 0..9 (masked to zero outside)
        float f[10];
        f[0] = mm   ? qm.y : 0.f;
        f[1] = mm   ? qm.z : 0.f;
        f[2] = mm   ? qm.w : 0.f;
        f[3] = mrow ? q0.x : 0.f;
        f[4] = mrow ? q0.y : 0.f;
        f[5] = mrow ? q0.z : 0.f;
        f[6] = mrow ? q0.w : 0.f;
        f[7] = mp   ? qp.x : 0.f;
        f[8] = mp   ? qp.y : 0.f;
        f[9] = mp   ? qp.z : 0.f;

        // sliding half2 pairs: pk[t] = (f[t], f[t+1])
        v2h pk[8];
#pragma unroll
        for (int t = 0; t < 8; ++t) pk[t] = pack2(f[t], f[t + 1]);

        // output row oi (kr = j - oi), col wb+jj: taps -> f[jj+kc]
#pragma unroll
        for (int oi = 0; oi < 4; ++oi) {
            const int kr = j - oi;
            if (kr >= 0 && kr < 7) {
#pragma unroll
                for (int jj = 0; jj < 4; ++jj) {
                    float a = fmaf(f[jj + 6], w6[kr], acc[oi][jj]);
                    a = __builtin_amdgcn_fdot2(pk[jj + 4], W[kr][2], a, false);
                    a = __builtin_amdgcn_fdot2(pk[jj + 2], W[kr][1], a, false);
                    a = __builtin_amdgcn_fdot2(pk[jj],     W[kr][0], a, false);
                    acc[oi][jj] = a;
                }
            }
        }
    }

    // ---- write 4 rows x float4, plus bias ----
    float* op = out + (size_t)plane * 4096 + (size_t)hb * 64 + wb;
#pragma unroll
    for (int oi = 0; oi < 4; ++oi) {
        float4 v;
        v.x = acc[oi][0] + bv;
        v.y = acc[oi][1] + bv;
        v.z = acc[oi][2] + bv;
        v.w = acc[oi][3] + bv;
        *reinterpret_cast<float4*>(op + oi * 64) = v;
    }
}

extern "C" void kernel_launch(void* const* d_in, const int* in_sizes, int n_in,
                              void* d_out, int out_size, void* d_ws, size_t ws_size,
                              hipStream_t stream) {
    const float* x      = (const float*)d_in[0];
    const float* weight = (const float*)d_in[1];
    const float* bias   = (const float*)d_in[2];
    float* out          = (float*)d_out;
    (void)in_sizes; (void)n_in; (void)out_size; (void)d_ws; (void)ws_size;

    // 16384 waves = 4096 blocks x 256 threads (4 waves/block)
    dim3 grid(4096);
    dim3 block(256);
    dwconv7x7_quarter<<<grid, block, 0, stream>>>(x, weight, bias, out);
}

// Round 14
// 32.016 us; speedup vs baseline: 1.5082x; 1.0988x over previous
//
#include <hip/hip_runtime.h>

// Depthwise 7x7 'same' conv, fp32 in/out. B=16, C=256, H=W=64.
// R10 geometry+math EXACTLY (verified best: wave = half-plane, lane =
// 4w x 8h tile, 32 f32 acc, dot2 inner product, absmax 0.25).
// NEW: source-level distance-5 load pipeline. Row j's 3 dwordx4 go into
// statically-indexed L[j][0..2] (full unroll -> VGPR-promoted), issued
// 5 steps before consumption. 15 outstanding loads/wave by DATAFLOW
// (no ring reuse -> allocator cannot collapse it; no asm, no vmcnt).
// lb(256,2) gives the 256-VGPR budget (R8: 124 VGPR spill-free there).
// Rationale: harness L3-flush per replay -> ~900cy HBM misses; all
// variants plateau at 36-40% duty -> latency-bound, MLP too shallow.

typedef _Float16 v2h __attribute__((ext_vector_type(2)));

static __device__ __forceinline__ v2h pack2(float a, float b) {
    return __builtin_bit_cast(v2h, __builtin_amdgcn_cvt_pkrtz(a, b));
}

__global__ __launch_bounds__(256, 2)
void dwconv7x7_dist5(const float* __restrict__ x,
                     const float* __restrict__ weight,
                     const float* __restrict__ bias,
                     float* __restrict__ out) {
    const int tid  = threadIdx.x;
    const int lane = tid & 63;
    const int wid  = tid >> 6;
    const int gw   = blockIdx.x * 4 + wid;   // 0..8191
    const int plane = gw >> 1;               // b*256 + c
    const int half  = gw & 1;
    const int c = __builtin_amdgcn_readfirstlane(plane & 255);

    // ---- per-channel weights (uniform): half2 pairs in SGPRs ----
    const float* wp = weight + c * 49;
    float wk[49];
#pragma unroll
    for (int k = 0; k < 49; ++k) wk[k] = wp[k];
    const float bv = bias[c];

    v2h  W[7][3];     // taps (0,1),(2,3),(4,5) per kernel row
    float w6[7];      // tap 6 scalar
#pragma unroll
    for (int kr = 0; kr < 7; ++kr) {
#pragma unroll
        for (int t = 0; t < 3; ++t) {
            v2h p = pack2(wk[kr * 7 + 2 * t], wk[kr * 7 + 2 * t + 1]);
            int b = __builtin_amdgcn_readfirstlane(__builtin_bit_cast(int, p));
            W[kr][t] = __builtin_bit_cast(v2h, b);
        }
        w6[kr] = wk[kr * 7 + 6];
    }

    const int tx = lane & 15;        // 16 tiles across width
    const int sy = lane >> 4;        // 4 strips per half-plane
    const int wb = tx * 4;           // output col base
    const int hb = half * 32 + sy * 8;

    const float* xp = x + (size_t)plane * 4096;
    const int offm = (tx > 0)  ? (wb - 4) : wb;   // clamped aligned left
    const int offp = (tx < 15) ? (wb + 4) : wb;   // clamped aligned right

    float acc[8][4];
#pragma unroll
    for (int i = 0; i < 8; ++i)
#pragma unroll
        for (int j = 0; j < 4; ++j) acc[i][j] = 0.f;

    // load pipeline: L[j] holds row (hb-3+j)'s 3 dwordx4. All indices
    // become compile-time constants after unrolling -> register-promoted.
    float4 L[14][3];

#define ISSUE(J) do {                                              \
        const int rr_ = min(max(hb - 3 + (J), 0), 63);             \
        const float* rowp_ = xp + rr_ * 64;                        \
        L[J][0] = *reinterpret_cast<const float4*>(rowp_ + offm);  \
        L[J][1] = *reinterpret_cast<const float4*>(rowp_ + wb);    \
        L[J][2] = *reinterpret_cast<const float4*>(rowp_ + offp);  \
    } while (0)

    // prologue: rows 0..4 in flight (15 loads)
#pragma unroll
    for (int j = 0; j < 5; ++j) ISSUE(j);

#pragma unroll
    for (int j = 0; j < 14; ++j) {
        const int r = hb - 3 + j;
        const bool mrow = (r >= 0) && (r < 64);
        const bool mm = mrow && (tx > 0);
        const bool mp = mrow && (tx < 15);

        // f[i] = x[r][wb-3+i], i = 0..9 (masked to zero outside)
        float f[10];
        f[0] = mm   ? L[j][0].y : 0.f;
        f[1] = mm   ? L[j][0].z : 0.f;
        f[2] = mm   ? L[j][0].w : 0.f;
        f[3] = mrow ? L[j][1].x : 0.f;
        f[4] = mrow ? L[j][1].y : 0.f;
        f[5] = mrow ? L[j][1].z : 0.f;
        f[6] = mrow ? L[j][1].w : 0.f;
        f[7] = mp   ? L[j][2].x : 0.f;
        f[8] = mp   ? L[j][2].y : 0.f;
        f[9] = mp   ? L[j][2].z : 0.f;

        // keep the pipeline 5 ahead
        if (j + 5 < 14) ISSUE(j + 5);

        // sliding half2 pairs: pk[t] = (f[t], f[t+1])
        v2h pk[8];
#pragma unroll
        for (int t = 0; t < 8; ++t) pk[t] = pack2(f[t], f[t + 1]);

        // output row oi (kr = j - oi), col wb+jj: taps -> f[jj+kc]
#pragma unroll
        for (int oi = 0; oi < 8; ++oi) {
            const int kr = j - oi;
            if (kr >= 0 && kr < 7) {
#pragma unroll
                for (int jj = 0; jj < 4; ++jj) {
                    float a = fmaf(f[jj + 6], w6[kr], acc[oi][jj]);
                    a = __builtin_amdgcn_fdot2(pk[jj + 4], W[kr][2], a, false);
                    a = __builtin_amdgcn_fdot2(pk[jj + 2], W[kr][1], a, false);
                    a = __builtin_amdgcn_fdot2(pk[jj],     W[kr][0], a, false);
                    acc[oi][jj] = a;
                }
            }
        }
    }
#undef ISSUE

    // ---- write 8 rows x float4, plus bias ----
    float* op = out + (size_t)plane * 4096 + (size_t)hb * 64 + wb;
#pragma unroll
    for (int oi = 0; oi < 8; ++oi) {
        float4 v;
        v.x = acc[oi][0] + bv;
        v.y = acc[oi][1] + bv;
        v.z = acc[oi][2] + bv;
        v.w = acc[oi][3] + bv;
        *reinterpret_cast<float4*>(op + oi * 64) = v;
    }
}

extern "C" void kernel_launch(void* const* d_in, const int* in_sizes, int n_in,
                              void* d_out, int out_size, void* d_ws, size_t ws_size,
                              hipStream_t stream) {
    const float* x      = (const float*)d_in[0];
    const float* weight = (const float*)d_in[1];
    const float* bias   = (const float*)d_in[2];
    float* out          = (float*)d_out;
    (void)in_sizes; (void)n_in; (void)out_size; (void)d_ws; (void)ws_size;

    // 8192 waves = 2048 blocks x 256 threads (4 waves/block)
    dim3 grid(2048);
    dim3 block(256);
    dwconv7x7_dist5<<<grid, block, 0, stream>>>(x, weight, bias, out);
}